// Round 2
// baseline (602.433 us; speedup 1.0000x reference)
//
#include <hip/hip_runtime.h>
#include <stdint.h>

typedef float  f32x4  __attribute__((ext_vector_type(4)));
typedef short  s16x4  __attribute__((ext_vector_type(4)));
typedef short  s16x8  __attribute__((ext_vector_type(8)));

#define S_LEN 2048
#define D_K   64
#define NBH   32
#define VT_STRIDE (S_LEN + 32)   // pad V^T rows by 64B to stagger L2 sets

__device__ __forceinline__ short f2bf(float f) {
    uint32_t u = __builtin_bit_cast(uint32_t, f);
    u += 0x7fffu + ((u >> 16) & 1u);           // RNE
    return (short)(u >> 16);
}
__device__ __forceinline__ s16x4 cvt4(float4 f) {
    s16x4 r; r[0] = f2bf(f.x); r[1] = f2bf(f.y); r[2] = f2bf(f.z); r[3] = f2bf(f.w);
    return r;
}
__device__ __forceinline__ s16x8 cat(s16x4 a, s16x4 b) {
    return __builtin_shufflevector(a, b, 0, 1, 2, 3, 4, 5, 6, 7);
}

// ---------------- pre-pass: K -> bf16 row-major, V -> bf16 transposed ----------------
__global__ __launch_bounds__(256) void preconv(
    const float* __restrict__ K, const float* __restrict__ V,
    short* __restrict__ Kb, short* __restrict__ VT)
{
    const int bh  = blockIdx.x >> 6;
    const int seg = blockIdx.x & 63;           // 32 k-rows per segment
    const int tid = threadIdx.x;
    const float* Ks = K + ((size_t)bh * S_LEN + seg * 32) * D_K;
    const float* Vs = V + ((size_t)bh * S_LEN + seg * 32) * D_K;
    short* Kd  = Kb + ((size_t)bh * S_LEN + seg * 32) * D_K;
    short* VTd = VT + (size_t)bh * D_K * VT_STRIDE + seg * 32;

    for (int i = tid; i < 512; i += 256) {     // K: read-friendly order
        const int r = i >> 4, c = (i & 15) << 2;
        float4 f = *(const float4*)(Ks + r * D_K + c);
        *(s16x4*)(Kd + r * D_K + c) = cvt4(f);
    }
    for (int i = tid; i < 512; i += 256) {     // V: write-friendly order (transpose)
        const int r = i & 31, c = (i >> 5) << 2;
        float4 f = *(const float4*)(Vs + r * D_K + c);
        VTd[(size_t)(c + 0) * VT_STRIDE + r] = f2bf(f.x);
        VTd[(size_t)(c + 1) * VT_STRIDE + r] = f2bf(f.y);
        VTd[(size_t)(c + 2) * VT_STRIDE + r] = f2bf(f.z);
        VTd[(size_t)(c + 3) * VT_STRIDE + r] = f2bf(f.w);
    }
}

// ---------------- main: wave-independent, barrier-free, no LDS ----------------
__global__ __launch_bounds__(256) void attn_main(
    const float* __restrict__ Q, const short* __restrict__ Kb,
    const short* __restrict__ VT, float* __restrict__ outC,
    float* __restrict__ outS)
{
    const int tid  = threadIdx.x;
    const int lane = tid & 63;
    const int wv   = tid >> 6;
    // XCD-locality: xcd = blk&7 owns 4 heads; heavy strips first in dispatch order
    const int xcd   = blockIdx.x & 7;
    const int idx   = blockIdx.x >> 3;          // 0..127
    const int bh    = (xcd << 2) + (idx >> 5);  // 0..31
    const int inner = idx & 31;                 // 0..31
    const int strip = ((31 - inner) << 2) + wv; // 0..127, heavy first
    const int q0w   = strip << 4;               // this wave's 16 q rows
    const int l15   = lane & 15;
    const int d0    = (lane >> 4) << 2;
    const int qg    = q0w + l15;

    const short* Kbh = Kb + (size_t)bh * S_LEN * D_K;
    const short* VTh = VT + (size_t)bh * D_K * VT_STRIDE;
    float* outSb = outS + (size_t)bh * S_LEN * S_LEN;
    float* outCb = outC + (size_t)bh * S_LEN * D_K;

    // Q as MFMA B-fragments (proven layout from R0)
    s16x8 qf0, qf1;
    {
        const float4* qp = (const float4*)(Q + ((size_t)bh * S_LEN + qg) * D_K);
        qf0 = cat(cvt4(qp[d0 >> 2]),        cvt4(qp[(d0 + 16) >> 2]));
        qf1 = cat(cvt4(qp[(d0 + 32) >> 2]), cvt4(qp[(d0 + 48) >> 2]));
    }

    const int ntiles = (strip >> 1) + 1;
    const int nfull  = strip >> 1;              // tiles strictly below diagonal
    const float scale = 0.125f;                 // 1/sqrt(64)

    // ---------- phase 1: exact row sums ----------
    float lsum = 0.f;
    for (int t = 0; t < ntiles; ++t) {
        const int k0 = t << 5;
        #pragma unroll
        for (int s = 0; s < 2; ++s) {
            const short* kp = Kbh + (size_t)(k0 + 16 * s + l15) * D_K + d0;
            s16x8 a0 = cat(*(const s16x4*)kp,        *(const s16x4*)(kp + 16));
            s16x8 a1 = cat(*(const s16x4*)(kp + 32), *(const s16x4*)(kp + 48));
            f32x4 c1 = {0.f, 0.f, 0.f, 0.f};
            c1 = __builtin_amdgcn_mfma_f32_16x16x32_bf16(a0, qf0, c1, 0, 0, 0);
            c1 = __builtin_amdgcn_mfma_f32_16x16x32_bf16(a1, qf1, c1, 0, 0, 0);
            if (t < nfull) {
                #pragma unroll
                for (int r = 0; r < 4; ++r) lsum += __expf(c1[r] * scale);
            } else {
                const int kbase = k0 + 16 * s + d0;
                #pragma unroll
                for (int r = 0; r < 4; ++r)
                    if (kbase + r <= qg) lsum += __expf(c1[r] * scale);
            }
        }
    }
    lsum += __shfl_xor(lsum, 16);
    lsum += __shfl_xor(lsum, 32);
    const float rinv = 1.f / lsum;

    // ---------- phase 2: write probs + accumulate P·V ----------
    f32x4 ctx[4] = {{0,0,0,0},{0,0,0,0},{0,0,0,0},{0,0,0,0}};
    for (int t = 0; t < ntiles; ++t) {
        const int k0 = t << 5;
        s16x8 pf;
        #pragma unroll
        for (int s = 0; s < 2; ++s) {
            const short* kp = Kbh + (size_t)(k0 + 16 * s + l15) * D_K + d0;
            s16x8 a0 = cat(*(const s16x4*)kp,        *(const s16x4*)(kp + 16));
            s16x8 a1 = cat(*(const s16x4*)(kp + 32), *(const s16x4*)(kp + 48));
            f32x4 c1 = {0.f, 0.f, 0.f, 0.f};
            c1 = __builtin_amdgcn_mfma_f32_16x16x32_bf16(a0, qf0, c1, 0, 0, 0);
            c1 = __builtin_amdgcn_mfma_f32_16x16x32_bf16(a1, qf1, c1, 0, 0, 0);
            const int kbase = k0 + 16 * s + d0;
            f32x4 pw;
            if (t < nfull) {
                #pragma unroll
                for (int r = 0; r < 4; ++r) {
                    float pe = __expf(c1[r] * scale) * rinv;
                    pw[r] = pe; pf[4 * s + r] = f2bf(pe);
                }
            } else {
                #pragma unroll
                for (int r = 0; r < 4; ++r) {
                    float pe = (kbase + r <= qg) ? __expf(c1[r] * scale) * rinv : 0.f;
                    pw[r] = pe; pf[4 * s + r] = f2bf(pe);
                }
            }
            *(f32x4*)(outSb + (size_t)qg * S_LEN + kbase) = pw;
        }
        #pragma unroll
        for (int db = 0; db < 4; ++db) {
            const short* vp = VTh + (size_t)(db * 16 + l15) * VT_STRIDE + k0 + d0;
            s16x8 b = cat(*(const s16x4*)vp, *(const s16x4*)(vp + 16));
            ctx[db] = __builtin_amdgcn_mfma_f32_16x16x32_bf16(pf, b, ctx[db], 0, 0, 0);
        }
    }

    // context write (C/D layout: col=lane&15, row=4*(lane>>4)+r)
    #pragma unroll
    for (int db = 0; db < 4; ++db)
        #pragma unroll
        for (int r = 0; r < 4; ++r)
            outCb[(size_t)(q0w + d0 + r) * D_K + db * 16 + l15] = ctx[db][r];

    // zero-fill masked region of this strip's rows
    const int kz = ntiles << 5;
    const f32x4 z = {0.f, 0.f, 0.f, 0.f};
    for (int r = 0; r < 16; ++r) {
        float* rowp = outSb + (size_t)(q0w + r) * S_LEN;
        for (int k = kz + (lane << 2); k < S_LEN; k += 256)
            *(f32x4*)(rowp + k) = z;
    }
}

// ---------------- fallback (R0 kernel, proven) if ws too small ----------------
#define KSTRIDE 68
#define VSTRIDE 36
__global__ __launch_bounds__(256) void attn_causal_fb(
    const float* __restrict__ Q, const float* __restrict__ K,
    const float* __restrict__ V, float* __restrict__ outC,
    float* __restrict__ outS)
{
    __shared__ short Klds[32 * KSTRIDE];
    __shared__ short Vlds[64 * VSTRIDE];
    const int bh = blockIdx.x >> 5, q0 = (blockIdx.x & 31) << 6;
    const int tid = threadIdx.x, lane = tid & 63, wv = tid >> 6;
    const int q0w = q0 + (wv << 4), l15 = lane & 15, d0 = (lane >> 4) << 2;
    const int qg = q0w + l15, qhi = q0w + 15;
    const float* Kb = K + (size_t)bh * S_LEN * D_K;
    const float* Vb = V + (size_t)bh * S_LEN * D_K;
    float* outSb = outS + (size_t)bh * S_LEN * S_LEN;
    float* outCb = outC + (size_t)bh * S_LEN * D_K;
    s16x8 qf0, qf1;
    {
        const float4* qp = (const float4*)(Q + ((size_t)bh * S_LEN + qg) * D_K);
        qf0 = cat(cvt4(qp[d0 >> 2]), cvt4(qp[(d0 + 16) >> 2]));
        qf1 = cat(cvt4(qp[(d0 + 32) >> 2]), cvt4(qp[(d0 + 48) >> 2]));
    }
    const int npairs = (q0 >> 5) + 2;
    const float scale = 0.125f;
    float lsum = 0.f;
    for (int p = 0; p < npairs; ++p) {
        const int k0 = p << 5;
        for (int i = tid; i < 512; i += 256) {
            const int r = i >> 4, c = (i & 15) << 2;
            float4 f = *(const float4*)(Kb + (size_t)(k0 + r) * D_K + c);
            *(s16x4*)&Klds[r * KSTRIDE + c] = cvt4(f);
        }
        __syncthreads();
        if (k0 <= qhi) {
            #pragma unroll
            for (int s = 0; s < 2; ++s) {
                const short* kp = &Klds[(16 * s + l15) * KSTRIDE + d0];
                s16x8 a0 = cat(*(const s16x4*)kp, *(const s16x4*)(kp + 16));
                s16x8 a1 = cat(*(const s16x4*)(kp + 32), *(const s16x4*)(kp + 48));
                f32x4 c1 = {0.f, 0.f, 0.f, 0.f};
                c1 = __builtin_amdgcn_mfma_f32_16x16x32_bf16(a0, qf0, c1, 0, 0, 0);
                c1 = __builtin_amdgcn_mfma_f32_16x16x32_bf16(a1, qf1, c1, 0, 0, 0);
                const int kbase = k0 + 16 * s + d0;
                #pragma unroll
                for (int r = 0; r < 4; ++r)
                    if (kbase + r <= qg) lsum += __expf(c1[r] * scale);
            }
        }
        __syncthreads();
    }
    lsum += __shfl_xor(lsum, 16);
    lsum += __shfl_xor(lsum, 32);
    const float rinv = 1.f / lsum;
    f32x4 ctx[4] = {{0,0,0,0},{0,0,0,0},{0,0,0,0},{0,0,0,0}};
    for (int p = 0; p < npairs; ++p) {
        const int k0 = p << 5;
        for (int i = tid; i < 512; i += 256) {
            const int r = i >> 4, c = (i & 15) << 2;
            float4 f = *(const float4*)(Kb + (size_t)(k0 + r) * D_K + c);
            *(s16x4*)&Klds[r * KSTRIDE + c] = cvt4(f);
            float4 g = *(const float4*)(Vb + (size_t)(k0 + r) * D_K + c);
            Vlds[(c + 0) * VSTRIDE + r] = f2bf(g.x);
            Vlds[(c + 1) * VSTRIDE + r] = f2bf(g.y);
            Vlds[(c + 2) * VSTRIDE + r] = f2bf(g.z);
            Vlds[(c + 3) * VSTRIDE + r] = f2bf(g.w);
        }
        __syncthreads();
        if (k0 <= qhi) {
            s16x8 pf;
            #pragma unroll
            for (int s = 0; s < 2; ++s) {
                const short* kp = &Klds[(16 * s + l15) * KSTRIDE + d0];
                s16x8 a0 = cat(*(const s16x4*)kp, *(const s16x4*)(kp + 16));
                s16x8 a1 = cat(*(const s16x4*)(kp + 32), *(const s16x4*)(kp + 48));
                f32x4 c1 = {0.f, 0.f, 0.f, 0.f};
                c1 = __builtin_amdgcn_mfma_f32_16x16x32_bf16(a0, qf0, c1, 0, 0, 0);
                c1 = __builtin_amdgcn_mfma_f32_16x16x32_bf16(a1, qf1, c1, 0, 0, 0);
                const int kbase = k0 + 16 * s + d0;
                f32x4 pw;
                #pragma unroll
                for (int r = 0; r < 4; ++r) {
                    float pe = (kbase + r <= qg) ? __expf(c1[r] * scale) * rinv : 0.f;
                    pw[r] = pe;
                    pf[4 * s + r] = f2bf(pe);
                }
                *(f32x4*)(outSb + (size_t)qg * S_LEN + kbase) = pw;
            }
            #pragma unroll
            for (int db = 0; db < 4; ++db) {
                const short* vp = &Vlds[(db * 16 + l15) * VSTRIDE + d0];
                s16x8 b = cat(*(const s16x4*)vp, *(const s16x4*)(vp + 16));
                ctx[db] = __builtin_amdgcn_mfma_f32_16x16x32_bf16(pf, b, ctx[db], 0, 0, 0);
            }
        }
        __syncthreads();
    }
    #pragma unroll
    for (int db = 0; db < 4; ++db)
        #pragma unroll
        for (int r = 0; r < 4; ++r)
            outCb[(size_t)(q0w + d0 + r) * D_K + db * 16 + l15] = ctx[db][r];
    const int kz = ((qhi >> 5) + 1) << 5;
    const f32x4 z = {0.f, 0.f, 0.f, 0.f};
    for (int r = 0; r < 16; ++r) {
        float* rowp = outSb + (size_t)(q0w + r) * S_LEN;
        for (int k = kz + (lane << 2); k < S_LEN; k += 256)
            *(f32x4*)(rowp + k) = z;
    }
}

extern "C" void kernel_launch(void* const* d_in, const int* in_sizes, int n_in,
                              void* d_out, int out_size, void* d_ws, size_t ws_size,
                              hipStream_t stream) {
    const float* Q = (const float*)d_in[0];
    const float* K = (const float*)d_in[1];
    const float* V = (const float*)d_in[2];
    float* outC = (float*)d_out;
    float* outS = (float*)d_out + (size_t)NBH * S_LEN * D_K;

    const size_t kb_elems = (size_t)NBH * S_LEN * D_K;            // bf16 K
    const size_t vt_elems = (size_t)NBH * D_K * VT_STRIDE;        // bf16 V^T
    const size_t need = (kb_elems + vt_elems) * sizeof(short);

    if (ws_size >= need) {
        short* Kb = (short*)d_ws;
        short* VT = Kb + kb_elems;
        preconv<<<dim3(NBH * 64), dim3(256), 0, stream>>>(K, V, Kb, VT);
        attn_main<<<dim3(1024), dim3(256), 0, stream>>>(Q, Kb, VT, outC, outS);
    } else {
        attn_causal_fb<<<dim3(1024), dim3(256), 0, stream>>>(Q, K, V, outC, outS);
    }
}

// Round 3
// 368.776 us; speedup vs baseline: 1.6336x; 1.6336x over previous
//
#include <hip/hip_runtime.h>
#include <stdint.h>

typedef float  f32x4  __attribute__((ext_vector_type(4)));
typedef short  s16x4  __attribute__((ext_vector_type(4)));
typedef short  s16x8  __attribute__((ext_vector_type(8)));

#define S_LEN 2048
#define D_K   64
#define NBH   32
#define VT_STRIDE (S_LEN + 32)   // pad V^T rows to stagger L2 sets

__device__ __forceinline__ short f2bf(float f) {
    uint32_t u = __builtin_bit_cast(uint32_t, f);
    u += 0x7fffu + ((u >> 16) & 1u);           // RNE
    return (short)(u >> 16);
}
__device__ __forceinline__ s16x4 cvt4(float4 f) {
    s16x4 r; r[0] = f2bf(f.x); r[1] = f2bf(f.y); r[2] = f2bf(f.z); r[3] = f2bf(f.w);
    return r;
}
__device__ __forceinline__ s16x8 cat(s16x4 a, s16x4 b) {
    return __builtin_shufflevector(a, b, 0, 1, 2, 3, 4, 5, 6, 7);
}

// ---------------- pre-pass: K -> bf16 row-major, V -> bf16 transposed ----------------
__global__ __launch_bounds__(256) void preconv(
    const float* __restrict__ K, const float* __restrict__ V,
    short* __restrict__ Kb, short* __restrict__ VT)
{
    const int bh  = blockIdx.x >> 6;
    const int seg = blockIdx.x & 63;
    const int tid = threadIdx.x;
    const float* Ks = K + ((size_t)bh * S_LEN + seg * 32) * D_K;
    const float* Vs = V + ((size_t)bh * S_LEN + seg * 32) * D_K;
    short* Kd  = Kb + ((size_t)bh * S_LEN + seg * 32) * D_K;
    short* VTd = VT + (size_t)bh * D_K * VT_STRIDE + seg * 32;

    for (int i = tid; i < 512; i += 256) {
        const int r = i >> 4, c = (i & 15) << 2;
        float4 f = *(const float4*)(Ks + r * D_K + c);
        *(s16x4*)(Kd + r * D_K + c) = cvt4(f);
    }
    for (int i = tid; i < 512; i += 256) {
        const int r = i & 31, c = (i >> 5) << 2;
        float4 f = *(const float4*)(Vs + r * D_K + c);
        VTd[(size_t)(c + 0) * VT_STRIDE + r] = f2bf(f.x);
        VTd[(size_t)(c + 1) * VT_STRIDE + r] = f2bf(f.y);
        VTd[(size_t)(c + 2) * VT_STRIDE + r] = f2bf(f.z);
        VTd[(size_t)(c + 3) * VT_STRIDE + r] = f2bf(f.w);
    }
}

// ---- main: one 16-row q-strip per block, k-tiles split across the 4 waves ----
#define CSTRIDE 66   // f32 elems per ctx-combine row (64 + 2 pad)
__global__ __launch_bounds__(256) void attn_strip(
    const float* __restrict__ Q, const short* __restrict__ Kb,
    const short* __restrict__ VT, float* __restrict__ outC,
    float* __restrict__ outS)
{
    __shared__ float cbuf[4][16][CSTRIDE];   // per-wave partial ctx
    __shared__ float lbuf[4][16];            // per-wave partial row sums

    const int tid  = threadIdx.x;
    const int lane = tid & 63;
    const int wv   = tid >> 6;
    const int xcd  = blockIdx.x & 7;
    const int idx  = blockIdx.x >> 3;            // 0..511
    const int bh   = (xcd << 2) + (idx >> 7);    // 0..31, 4 heads per XCD
    const int strip = 127 - (idx & 127);         // heavy strips dispatched first
    const int q0w  = strip << 4;                 // strip's 16 q rows
    const int l15  = lane & 15;
    const int d0   = (lane >> 4) << 2;           // {0,4,8,12}
    const int qg   = q0w + l15;

    const short* Kbh = Kb + (size_t)bh * S_LEN * D_K;
    const short* VTh = VT + (size_t)bh * D_K * VT_STRIDE;
    float* outSb = outS + (size_t)bh * S_LEN * S_LEN;
    float* outCb = outC + (size_t)bh * S_LEN * D_K;

    // Q as MFMA B-fragments (layout proven R0-R2)
    s16x8 qf0, qf1;
    {
        const float4* qp = (const float4*)(Q + ((size_t)bh * S_LEN + qg) * D_K);
        qf0 = cat(cvt4(qp[d0 >> 2]),        cvt4(qp[(d0 + 16) >> 2]));
        qf1 = cat(cvt4(qp[(d0 + 32) >> 2]), cvt4(qp[(d0 + 48) >> 2]));
    }

    const int ntiles = (strip >> 1) + 1;
    const int nfull  = strip >> 1;
    const float scale = 0.125f;                  // 1/sqrt(64)

    // ---------- phase 1: partial row sums over this wave's k-tiles ----------
    float lsum = 0.f;
    for (int t = wv; t < ntiles; t += 4) {
        const int k0 = t << 5;
        #pragma unroll
        for (int s = 0; s < 2; ++s) {
            const short* kp = Kbh + (size_t)(k0 + 16 * s + l15) * D_K + d0;
            s16x8 a0 = cat(*(const s16x4*)kp,        *(const s16x4*)(kp + 16));
            s16x8 a1 = cat(*(const s16x4*)(kp + 32), *(const s16x4*)(kp + 48));
            f32x4 c1 = {0.f, 0.f, 0.f, 0.f};
            c1 = __builtin_amdgcn_mfma_f32_16x16x32_bf16(a0, qf0, c1, 0, 0, 0);
            c1 = __builtin_amdgcn_mfma_f32_16x16x32_bf16(a1, qf1, c1, 0, 0, 0);
            if (t < nfull) {
                #pragma unroll
                for (int r = 0; r < 4; ++r) lsum += __expf(c1[r] * scale);
            } else {
                const int kbase = k0 + 16 * s + d0;
                #pragma unroll
                for (int r = 0; r < 4; ++r)
                    if (kbase + r <= qg) lsum += __expf(c1[r] * scale);
            }
        }
    }
    lsum += __shfl_xor(lsum, 16);
    lsum += __shfl_xor(lsum, 32);
    if (lane < 16) lbuf[wv][l15] = lsum;
    __syncthreads();
    const float rinv = 1.f / (lbuf[0][l15] + lbuf[1][l15] + lbuf[2][l15] + lbuf[3][l15]);

    // ---------- phase 2: write probs + partial P·V over this wave's k-tiles ----------
    f32x4 ctx[4] = {{0,0,0,0},{0,0,0,0},{0,0,0,0},{0,0,0,0}};
    for (int t = wv; t < ntiles; t += 4) {
        const int k0 = t << 5;
        s16x8 pf;
        #pragma unroll
        for (int s = 0; s < 2; ++s) {
            const short* kp = Kbh + (size_t)(k0 + 16 * s + l15) * D_K + d0;
            s16x8 a0 = cat(*(const s16x4*)kp,        *(const s16x4*)(kp + 16));
            s16x8 a1 = cat(*(const s16x4*)(kp + 32), *(const s16x4*)(kp + 48));
            f32x4 c1 = {0.f, 0.f, 0.f, 0.f};
            c1 = __builtin_amdgcn_mfma_f32_16x16x32_bf16(a0, qf0, c1, 0, 0, 0);
            c1 = __builtin_amdgcn_mfma_f32_16x16x32_bf16(a1, qf1, c1, 0, 0, 0);
            const int kbase = k0 + 16 * s + d0;
            f32x4 pw;
            if (t < nfull) {
                #pragma unroll
                for (int r = 0; r < 4; ++r) {
                    float pe = __expf(c1[r] * scale) * rinv;
                    pw[r] = pe; pf[4 * s + r] = f2bf(pe);
                }
            } else {
                #pragma unroll
                for (int r = 0; r < 4; ++r) {
                    float pe = (kbase + r <= qg) ? __expf(c1[r] * scale) * rinv : 0.f;
                    pw[r] = pe; pf[4 * s + r] = f2bf(pe);
                }
            }
            *(f32x4*)(outSb + (size_t)qg * S_LEN + kbase) = pw;
        }
        #pragma unroll
        for (int db = 0; db < 4; ++db) {
            const short* vp = VTh + (size_t)(db * 16 + l15) * VT_STRIDE + k0 + d0;
            s16x8 b = cat(*(const s16x4*)vp, *(const s16x4*)(vp + 16));
            ctx[db] = __builtin_amdgcn_mfma_f32_16x16x32_bf16(pf, b, ctx[db], 0, 0, 0);
        }
    }

    // combine partial ctx across the 4 waves via LDS
    #pragma unroll
    for (int db = 0; db < 4; ++db)
        #pragma unroll
        for (int r = 0; r < 4; ++r)
            cbuf[wv][d0 + r][db * 16 + l15] = ctx[db][r];
    __syncthreads();
    {
        const int row = tid >> 4, dbase = (tid & 15) << 2;
        f32x4 acc = *(const f32x4*)&cbuf[0][row][dbase];
        #pragma unroll
        for (int w = 1; w < 4; ++w) {
            f32x4 p = *(const f32x4*)&cbuf[w][row][dbase];
            acc[0] += p[0]; acc[1] += p[1]; acc[2] += p[2]; acc[3] += p[3];
        }
        *(f32x4*)(outCb + (size_t)(q0w + row) * D_K + dbase) = acc;
    }

    // zero-fill masked region (k >= kz) of the strip's 16 rows
    const int kz = ntiles << 5;
    const f32x4 z = {0.f, 0.f, 0.f, 0.f};
    {
        const int row = tid >> 4;
        float* rowp = outSb + (size_t)(q0w + row) * S_LEN;
        for (int k = kz + ((tid & 15) << 2); k < S_LEN; k += 64)
            *(f32x4*)(rowp + k) = z;
    }
}

// ---------------- fallback (R0 kernel, proven) if ws too small ----------------
#define KSTRIDE 68
#define VSTRIDE 36
__global__ __launch_bounds__(256) void attn_causal_fb(
    const float* __restrict__ Q, const float* __restrict__ K,
    const float* __restrict__ V, float* __restrict__ outC,
    float* __restrict__ outS)
{
    __shared__ short Klds[32 * KSTRIDE];
    __shared__ short Vlds[64 * VSTRIDE];
    const int bh = blockIdx.x >> 5, q0 = (blockIdx.x & 31) << 6;
    const int tid = threadIdx.x, lane = tid & 63, wv = tid >> 6;
    const int q0w = q0 + (wv << 4), l15 = lane & 15, d0 = (lane >> 4) << 2;
    const int qg = q0w + l15, qhi = q0w + 15;
    const float* Kb = K + (size_t)bh * S_LEN * D_K;
    const float* Vb = V + (size_t)bh * S_LEN * D_K;
    float* outSb = outS + (size_t)bh * S_LEN * S_LEN;
    float* outCb = outC + (size_t)bh * S_LEN * D_K;
    s16x8 qf0, qf1;
    {
        const float4* qp = (const float4*)(Q + ((size_t)bh * S_LEN + qg) * D_K);
        qf0 = cat(cvt4(qp[d0 >> 2]), cvt4(qp[(d0 + 16) >> 2]));
        qf1 = cat(cvt4(qp[(d0 + 32) >> 2]), cvt4(qp[(d0 + 48) >> 2]));
    }
    const int npairs = (q0 >> 5) + 2;
    const float scale = 0.125f;
    float lsum = 0.f;
    for (int p = 0; p < npairs; ++p) {
        const int k0 = p << 5;
        for (int i = tid; i < 512; i += 256) {
            const int r = i >> 4, c = (i & 15) << 2;
            float4 f = *(const float4*)(Kb + (size_t)(k0 + r) * D_K + c);
            *(s16x4*)&Klds[r * KSTRIDE + c] = cvt4(f);
        }
        __syncthreads();
        if (k0 <= qhi) {
            #pragma unroll
            for (int s = 0; s < 2; ++s) {
                const short* kp = &Klds[(16 * s + l15) * KSTRIDE + d0];
                s16x8 a0 = cat(*(const s16x4*)kp, *(const s16x4*)(kp + 16));
                s16x8 a1 = cat(*(const s16x4*)(kp + 32), *(const s16x4*)(kp + 48));
                f32x4 c1 = {0.f, 0.f, 0.f, 0.f};
                c1 = __builtin_amdgcn_mfma_f32_16x16x32_bf16(a0, qf0, c1, 0, 0, 0);
                c1 = __builtin_amdgcn_mfma_f32_16x16x32_bf16(a1, qf1, c1, 0, 0, 0);
                const int kbase = k0 + 16 * s + d0;
                #pragma unroll
                for (int r = 0; r < 4; ++r)
                    if (kbase + r <= qg) lsum += __expf(c1[r] * scale);
            }
        }
        __syncthreads();
    }
    lsum += __shfl_xor(lsum, 16);
    lsum += __shfl_xor(lsum, 32);
    const float rinv = 1.f / lsum;
    f32x4 ctx[4] = {{0,0,0,0},{0,0,0,0},{0,0,0,0},{0,0,0,0}};
    for (int p = 0; p < npairs; ++p) {
        const int k0 = p << 5;
        for (int i = tid; i < 512; i += 256) {
            const int r = i >> 4, c = (i & 15) << 2;
            float4 f = *(const float4*)(Kb + (size_t)(k0 + r) * D_K + c);
            *(s16x4*)&Klds[r * KSTRIDE + c] = cvt4(f);
            float4 g = *(const float4*)(Vb + (size_t)(k0 + r) * D_K + c);
            Vlds[(c + 0) * VSTRIDE + r] = f2bf(g.x);
            Vlds[(c + 1) * VSTRIDE + r] = f2bf(g.y);
            Vlds[(c + 2) * VSTRIDE + r] = f2bf(g.z);
            Vlds[(c + 3) * VSTRIDE + r] = f2bf(g.w);
        }
        __syncthreads();
        if (k0 <= qhi) {
            s16x8 pf;
            #pragma unroll
            for (int s = 0; s < 2; ++s) {
                const short* kp = &Klds[(16 * s + l15) * KSTRIDE + d0];
                s16x8 a0 = cat(*(const s16x4*)kp, *(const s16x4*)(kp + 16));
                s16x8 a1 = cat(*(const s16x4*)(kp + 32), *(const s16x4*)(kp + 48));
                f32x4 c1 = {0.f, 0.f, 0.f, 0.f};
                c1 = __builtin_amdgcn_mfma_f32_16x16x32_bf16(a0, qf0, c1, 0, 0, 0);
                c1 = __builtin_amdgcn_mfma_f32_16x16x32_bf16(a1, qf1, c1, 0, 0, 0);
                const int kbase = k0 + 16 * s + d0;
                f32x4 pw;
                #pragma unroll
                for (int r = 0; r < 4; ++r) {
                    float pe = (kbase + r <= qg) ? __expf(c1[r] * scale) * rinv : 0.f;
                    pw[r] = pe;
                    pf[4 * s + r] = f2bf(pe);
                }
                *(f32x4*)(outSb + (size_t)qg * S_LEN + kbase) = pw;
            }
            #pragma unroll
            for (int db = 0; db < 4; ++db) {
                const short* vp = &Vlds[(db * 16 + l15) * VSTRIDE + d0];
                s16x8 b = cat(*(const s16x4*)vp, *(const s16x4*)(vp + 16));
                ctx[db] = __builtin_amdgcn_mfma_f32_16x16x32_bf16(pf, b, ctx[db], 0, 0, 0);
            }
        }
        __syncthreads();
    }
    #pragma unroll
    for (int db = 0; db < 4; ++db)
        #pragma unroll
        for (int r = 0; r < 4; ++r)
            outCb[(size_t)(q0w + d0 + r) * D_K + db * 16 + l15] = ctx[db][r];
    const int kz = ((qhi >> 5) + 1) << 5;
    const f32x4 z = {0.f, 0.f, 0.f, 0.f};
    for (int r = 0; r < 16; ++r) {
        float* rowp = outSb + (size_t)(q0w + r) * S_LEN;
        for (int k = kz + (lane << 2); k < S_LEN; k += 256)
            *(f32x4*)(rowp + k) = z;
    }
}

extern "C" void kernel_launch(void* const* d_in, const int* in_sizes, int n_in,
                              void* d_out, int out_size, void* d_ws, size_t ws_size,
                              hipStream_t stream) {
    const float* Q = (const float*)d_in[0];
    const float* K = (const float*)d_in[1];
    const float* V = (const float*)d_in[2];
    float* outC = (float*)d_out;
    float* outS = (float*)d_out + (size_t)NBH * S_LEN * D_K;

    const size_t kb_elems = (size_t)NBH * S_LEN * D_K;
    const size_t vt_elems = (size_t)NBH * D_K * VT_STRIDE;
    const size_t need = (kb_elems + vt_elems) * sizeof(short);

    if (ws_size >= need) {
        short* Kb = (short*)d_ws;
        short* VT = Kb + kb_elems;
        preconv<<<dim3(NBH * 64), dim3(256), 0, stream>>>(K, V, Kb, VT);
        attn_strip<<<dim3(4096), dim3(256), 0, stream>>>(Q, Kb, VT, outC, outS);
    } else {
        attn_causal_fb<<<dim3(1024), dim3(256), 0, stream>>>(Q, K, V, outC, outS);
    }
}

// Round 4
// 356.402 us; speedup vs baseline: 1.6903x; 1.0347x over previous
//
#include <hip/hip_runtime.h>
#include <stdint.h>

typedef float  f32x4  __attribute__((ext_vector_type(4)));
typedef short  s16x4  __attribute__((ext_vector_type(4)));
typedef short  s16x8  __attribute__((ext_vector_type(8)));

#define S_LEN 2048
#define D_K   64
#define NBH   32
#define VT_STRIDE (S_LEN + 32)   // pad V^T rows to stagger L2 sets

__device__ __forceinline__ short f2bf(float f) {
    uint32_t u = __builtin_bit_cast(uint32_t, f);
    u += 0x7fffu + ((u >> 16) & 1u);           // RNE
    return (short)(u >> 16);
}
__device__ __forceinline__ s16x4 cvt4(float4 f) {
    s16x4 r; r[0] = f2bf(f.x); r[1] = f2bf(f.y); r[2] = f2bf(f.z); r[3] = f2bf(f.w);
    return r;
}
__device__ __forceinline__ s16x8 cat(s16x4 a, s16x4 b) {
    return __builtin_shufflevector(a, b, 0, 1, 2, 3, 4, 5, 6, 7);
}
__device__ __forceinline__ void nt_store4(float* p, f32x4 v) {
    __builtin_nontemporal_store(v, (f32x4*)p);   // global_store_dwordx4 ... nt
}

// ---------------- pre-pass: K -> bf16 row-major, V -> bf16 transposed ----------------
__global__ __launch_bounds__(256) void preconv(
    const float* __restrict__ K, const float* __restrict__ V,
    short* __restrict__ Kb, short* __restrict__ VT)
{
    const int bh  = blockIdx.x >> 6;
    const int seg = blockIdx.x & 63;
    const int tid = threadIdx.x;
    const float* Ks = K + ((size_t)bh * S_LEN + seg * 32) * D_K;
    const float* Vs = V + ((size_t)bh * S_LEN + seg * 32) * D_K;
    short* Kd  = Kb + ((size_t)bh * S_LEN + seg * 32) * D_K;
    short* VTd = VT + (size_t)bh * D_K * VT_STRIDE + seg * 32;

    for (int i = tid; i < 512; i += 256) {
        const int r = i >> 4, c = (i & 15) << 2;
        float4 f = *(const float4*)(Ks + r * D_K + c);
        *(s16x4*)(Kd + r * D_K + c) = cvt4(f);
    }
    for (int i = tid; i < 512; i += 256) {
        const int r = i & 31, c = (i >> 5) << 2;
        float4 f = *(const float4*)(Vs + r * D_K + c);
        VTd[(size_t)(c + 0) * VT_STRIDE + r] = f2bf(f.x);
        VTd[(size_t)(c + 1) * VT_STRIDE + r] = f2bf(f.y);
        VTd[(size_t)(c + 2) * VT_STRIDE + r] = f2bf(f.z);
        VTd[(size_t)(c + 3) * VT_STRIDE + r] = f2bf(f.w);
    }
}

// ---- main: one 16-row q-strip per block; waves own CONTIGUOUS k-tile ranges ----
#define CSTRIDE 66   // f32 elems per ctx-combine row (64 + 2 pad)
__global__ __launch_bounds__(256) void attn_strip(
    const float* __restrict__ Q, const short* __restrict__ Kb,
    const short* __restrict__ VT, float* __restrict__ outC,
    float* __restrict__ outS)
{
    __shared__ float cbuf[4][16][CSTRIDE];   // per-wave partial ctx
    __shared__ float lbuf[4][16];            // per-wave partial row sums

    const int tid  = threadIdx.x;
    const int lane = tid & 63;
    const int wv   = tid >> 6;
    const int xcd  = blockIdx.x & 7;
    const int idx  = blockIdx.x >> 3;            // 0..511
    const int bh   = (xcd << 2) + (idx >> 7);    // 0..31, 4 heads per XCD
    const int strip = 127 - (idx & 127);         // heavy strips dispatched first
    const int q0w  = strip << 4;                 // strip's 16 q rows
    const int l15  = lane & 15;
    const int d0   = (lane >> 4) << 2;           // {0,4,8,12}
    const int qg   = q0w + l15;

    const short* Kbh = Kb + (size_t)bh * S_LEN * D_K;
    const short* VTh = VT + (size_t)bh * D_K * VT_STRIDE;
    float* outSb = outS + (size_t)bh * S_LEN * S_LEN;
    float* outCb = outC + (size_t)bh * S_LEN * D_K;

    // Q as MFMA B-fragments (layout proven R0-R3)
    s16x8 qf0, qf1;
    {
        const float4* qp = (const float4*)(Q + ((size_t)bh * S_LEN + qg) * D_K);
        qf0 = cat(cvt4(qp[d0 >> 2]),        cvt4(qp[(d0 + 16) >> 2]));
        qf1 = cat(cvt4(qp[(d0 + 32) >> 2]), cvt4(qp[(d0 + 48) >> 2]));
    }

    const int ntiles = (strip >> 1) + 1;
    const int nfull  = strip >> 1;               // tiles strictly below diagonal
    const int nt4    = (ntiles + 3) >> 2;
    const int t0     = wv * nt4;
    const int t1     = (t0 + nt4 < ntiles) ? (t0 + nt4) : ntiles;
    const float scale = 0.125f;                  // 1/sqrt(64)

    // ---------- phase 1: partial row sums over this wave's contiguous k-range ----------
    float lsum = 0.f;
    for (int t = t0; t < t1; ++t) {
        const int k0 = t << 5;
        #pragma unroll
        for (int s = 0; s < 2; ++s) {
            const short* kp = Kbh + (size_t)(k0 + 16 * s + l15) * D_K + d0;
            s16x8 a0 = cat(*(const s16x4*)kp,        *(const s16x4*)(kp + 16));
            s16x8 a1 = cat(*(const s16x4*)(kp + 32), *(const s16x4*)(kp + 48));
            f32x4 c1 = {0.f, 0.f, 0.f, 0.f};
            c1 = __builtin_amdgcn_mfma_f32_16x16x32_bf16(a0, qf0, c1, 0, 0, 0);
            c1 = __builtin_amdgcn_mfma_f32_16x16x32_bf16(a1, qf1, c1, 0, 0, 0);
            if (t < nfull) {
                #pragma unroll
                for (int r = 0; r < 4; ++r) lsum += __expf(c1[r] * scale);
            } else {
                const int kbase = k0 + 16 * s + d0;
                #pragma unroll
                for (int r = 0; r < 4; ++r)
                    if (kbase + r <= qg) lsum += __expf(c1[r] * scale);
            }
        }
    }
    lsum += __shfl_xor(lsum, 16);
    lsum += __shfl_xor(lsum, 32);
    if (lane < 16) lbuf[wv][l15] = lsum;
    __syncthreads();
    const float rinv = 1.f / (lbuf[0][l15] + lbuf[1][l15] + lbuf[2][l15] + lbuf[3][l15]);

    // ---------- phase 2: nt-write probs + partial P·V ----------
    f32x4 ctx[4] = {{0,0,0,0},{0,0,0,0},{0,0,0,0},{0,0,0,0}};
    for (int t = t0; t < t1; ++t) {
        const int k0 = t << 5;
        s16x8 pf;
        #pragma unroll
        for (int s = 0; s < 2; ++s) {
            const short* kp = Kbh + (size_t)(k0 + 16 * s + l15) * D_K + d0;
            s16x8 a0 = cat(*(const s16x4*)kp,        *(const s16x4*)(kp + 16));
            s16x8 a1 = cat(*(const s16x4*)(kp + 32), *(const s16x4*)(kp + 48));
            f32x4 c1 = {0.f, 0.f, 0.f, 0.f};
            c1 = __builtin_amdgcn_mfma_f32_16x16x32_bf16(a0, qf0, c1, 0, 0, 0);
            c1 = __builtin_amdgcn_mfma_f32_16x16x32_bf16(a1, qf1, c1, 0, 0, 0);
            const int kbase = k0 + 16 * s + d0;
            f32x4 pw;
            if (t < nfull) {
                #pragma unroll
                for (int r = 0; r < 4; ++r) {
                    float pe = __expf(c1[r] * scale) * rinv;
                    pw[r] = pe; pf[4 * s + r] = f2bf(pe);
                }
            } else {
                #pragma unroll
                for (int r = 0; r < 4; ++r) {
                    float pe = (kbase + r <= qg) ? __expf(c1[r] * scale) * rinv : 0.f;
                    pw[r] = pe; pf[4 * s + r] = f2bf(pe);
                }
            }
            nt_store4(outSb + (size_t)qg * S_LEN + kbase, pw);
        }
        #pragma unroll
        for (int db = 0; db < 4; ++db) {
            const short* vp = VTh + (size_t)(db * 16 + l15) * VT_STRIDE + k0 + d0;
            s16x8 b = cat(*(const s16x4*)vp, *(const s16x4*)(vp + 16));
            ctx[db] = __builtin_amdgcn_mfma_f32_16x16x32_bf16(pf, b, ctx[db], 0, 0, 0);
        }
    }

    // combine partial ctx across the 4 waves via LDS
    #pragma unroll
    for (int db = 0; db < 4; ++db)
        #pragma unroll
        for (int r = 0; r < 4; ++r)
            cbuf[wv][d0 + r][db * 16 + l15] = ctx[db][r];
    __syncthreads();
    {
        const int row = tid >> 4, dbase = (tid & 15) << 2;
        f32x4 acc = *(const f32x4*)&cbuf[0][row][dbase];
        #pragma unroll
        for (int w = 1; w < 4; ++w) {
            f32x4 p = *(const f32x4*)&cbuf[w][row][dbase];
            acc[0] += p[0]; acc[1] += p[1]; acc[2] += p[2]; acc[3] += p[3];
        }
        *(f32x4*)(outCb + (size_t)(q0w + row) * D_K + dbase) = acc;
    }

    // zero-fill masked region (k >= kz) of the strip's 16 rows, nontemporal
    const int kz = ntiles << 5;
    const f32x4 z = {0.f, 0.f, 0.f, 0.f};
    {
        const int row = tid >> 4;
        float* rowp = outSb + (size_t)(q0w + row) * S_LEN;
        for (int k = kz + ((tid & 15) << 2); k < S_LEN; k += 64)
            nt_store4(rowp + k, z);
    }
}

// ---------------- fallback (R0 kernel, proven) if ws too small ----------------
#define KSTRIDE 68
#define VSTRIDE 36
__global__ __launch_bounds__(256) void attn_causal_fb(
    const float* __restrict__ Q, const float* __restrict__ K,
    const float* __restrict__ V, float* __restrict__ outC,
    float* __restrict__ outS)
{
    __shared__ short Klds[32 * KSTRIDE];
    __shared__ short Vlds[64 * VSTRIDE];
    const int bh = blockIdx.x >> 5, q0 = (blockIdx.x & 31) << 6;
    const int tid = threadIdx.x, lane = tid & 63, wv = tid >> 6;
    const int q0w = q0 + (wv << 4), l15 = lane & 15, d0 = (lane >> 4) << 2;
    const int qg = q0w + l15, qhi = q0w + 15;
    const float* Kb = K + (size_t)bh * S_LEN * D_K;
    const float* Vb = V + (size_t)bh * S_LEN * D_K;
    float* outSb = outS + (size_t)bh * S_LEN * S_LEN;
    float* outCb = outC + (size_t)bh * S_LEN * D_K;
    s16x8 qf0, qf1;
    {
        const float4* qp = (const float4*)(Q + ((size_t)bh * S_LEN + qg) * D_K);
        qf0 = cat(cvt4(qp[d0 >> 2]), cvt4(qp[(d0 + 16) >> 2]));
        qf1 = cat(cvt4(qp[(d0 + 32) >> 2]), cvt4(qp[(d0 + 48) >> 2]));
    }
    const int npairs = (q0 >> 5) + 2;
    const float scale = 0.125f;
    float lsum = 0.f;
    for (int p = 0; p < npairs; ++p) {
        const int k0 = p << 5;
        for (int i = tid; i < 512; i += 256) {
            const int r = i >> 4, c = (i & 15) << 2;
            float4 f = *(const float4*)(Kb + (size_t)(k0 + r) * D_K + c);
            *(s16x4*)&Klds[r * KSTRIDE + c] = cvt4(f);
        }
        __syncthreads();
        if (k0 <= qhi) {
            #pragma unroll
            for (int s = 0; s < 2; ++s) {
                const short* kp = &Klds[(16 * s + l15) * KSTRIDE + d0];
                s16x8 a0 = cat(*(const s16x4*)kp, *(const s16x4*)(kp + 16));
                s16x8 a1 = cat(*(const s16x4*)(kp + 32), *(const s16x4*)(kp + 48));
                f32x4 c1 = {0.f, 0.f, 0.f, 0.f};
                c1 = __builtin_amdgcn_mfma_f32_16x16x32_bf16(a0, qf0, c1, 0, 0, 0);
                c1 = __builtin_amdgcn_mfma_f32_16x16x32_bf16(a1, qf1, c1, 0, 0, 0);
                const int kbase = k0 + 16 * s + d0;
                #pragma unroll
                for (int r = 0; r < 4; ++r)
                    if (kbase + r <= qg) lsum += __expf(c1[r] * scale);
            }
        }
        __syncthreads();
    }
    lsum += __shfl_xor(lsum, 16);
    lsum += __shfl_xor(lsum, 32);
    const float rinv = 1.f / lsum;
    f32x4 ctx[4] = {{0,0,0,0},{0,0,0,0},{0,0,0,0},{0,0,0,0}};
    for (int p = 0; p < npairs; ++p) {
        const int k0 = p << 5;
        for (int i = tid; i < 512; i += 256) {
            const int r = i >> 4, c = (i & 15) << 2;
            float4 f = *(const float4*)(Kb + (size_t)(k0 + r) * D_K + c);
            *(s16x4*)&Klds[r * KSTRIDE + c] = cvt4(f);
            float4 g = *(const float4*)(Vb + (size_t)(k0 + r) * D_K + c);
            Vlds[(c + 0) * VSTRIDE + r] = f2bf(g.x);
            Vlds[(c + 1) * VSTRIDE + r] = f2bf(g.y);
            Vlds[(c + 2) * VSTRIDE + r] = f2bf(g.z);
            Vlds[(c + 3) * VSTRIDE + r] = f2bf(g.w);
        }
        __syncthreads();
        if (k0 <= qhi) {
            s16x8 pf;
            #pragma unroll
            for (int s = 0; s < 2; ++s) {
                const short* kp = &Klds[(16 * s + l15) * KSTRIDE + d0];
                s16x8 a0 = cat(*(const s16x4*)kp, *(const s16x4*)(kp + 16));
                s16x8 a1 = cat(*(const s16x4*)(kp + 32), *(const s16x4*)(kp + 48));
                f32x4 c1 = {0.f, 0.f, 0.f, 0.f};
                c1 = __builtin_amdgcn_mfma_f32_16x16x32_bf16(a0, qf0, c1, 0, 0, 0);
                c1 = __builtin_amdgcn_mfma_f32_16x16x32_bf16(a1, qf1, c1, 0, 0, 0);
                const int kbase = k0 + 16 * s + d0;
                f32x4 pw;
                #pragma unroll
                for (int r = 0; r < 4; ++r) {
                    float pe = (kbase + r <= qg) ? __expf(c1[r] * scale) * rinv : 0.f;
                    pw[r] = pe;
                    pf[4 * s + r] = f2bf(pe);
                }
                *(f32x4*)(outSb + (size_t)qg * S_LEN + kbase) = pw;
            }
            #pragma unroll
            for (int db = 0; db < 4; ++db) {
                const short* vp = &Vlds[(db * 16 + l15) * VSTRIDE + d0];
                s16x8 b = cat(*(const s16x4*)vp, *(const s16x4*)(vp + 16));
                ctx[db] = __builtin_amdgcn_mfma_f32_16x16x32_bf16(pf, b, ctx[db], 0, 0, 0);
            }
        }
        __syncthreads();
    }
    #pragma unroll
    for (int db = 0; db < 4; ++db)
        #pragma unroll
        for (int r = 0; r < 4; ++r)
            outCb[(size_t)(q0w + d0 + r) * D_K + db * 16 + l15] = ctx[db][r];
    const int kz = ((qhi >> 5) + 1) << 5;
    const f32x4 z = {0.f, 0.f, 0.f, 0.f};
    for (int r = 0; r < 16; ++r) {
        float* rowp = outSb + (size_t)(q0w + r) * S_LEN;
        for (int k = kz + (lane << 2); k < S_LEN; k += 256)
            *(f32x4*)(rowp + k) = z;
    }
}

extern "C" void kernel_launch(void* const* d_in, const int* in_sizes, int n_in,
                              void* d_out, int out_size, void* d_ws, size_t ws_size,
                              hipStream_t stream) {
    const float* Q = (const float*)d_in[0];
    const float* K = (const float*)d_in[1];
    const float* V = (const float*)d_in[2];
    float* outC = (float*)d_out;
    float* outS = (float*)d_out + (size_t)NBH * S_LEN * D_K;

    const size_t kb_elems = (size_t)NBH * S_LEN * D_K;
    const size_t vt_elems = (size_t)NBH * D_K * VT_STRIDE;
    const size_t need = (kb_elems + vt_elems) * sizeof(short);

    if (ws_size >= need) {
        short* Kb = (short*)d_ws;
        short* VT = Kb + kb_elems;
        preconv<<<dim3(NBH * 64), dim3(256), 0, stream>>>(K, V, Kb, VT);
        attn_strip<<<dim3(4096), dim3(256), 0, stream>>>(Q, Kb, VT, outC, outS);
    } else {
        attn_causal_fb<<<dim3(1024), dim3(256), 0, stream>>>(Q, K, V, outC, outS);
    }
}

// Round 5
// 347.052 us; speedup vs baseline: 1.7359x; 1.0269x over previous
//
#include <hip/hip_runtime.h>
#include <stdint.h>

typedef float  f32x4  __attribute__((ext_vector_type(4)));
typedef short  s16x4  __attribute__((ext_vector_type(4)));
typedef short  s16x8  __attribute__((ext_vector_type(8)));

#define S_LEN 2048
#define D_K   64
#define NBH   32
#define VT_STRIDE (S_LEN + 32)   // pad V^T rows to stagger L2 sets

__device__ __forceinline__ short f2bf(float f) {
    uint32_t u = __builtin_bit_cast(uint32_t, f);
    u += 0x7fffu + ((u >> 16) & 1u);           // RNE
    return (short)(u >> 16);
}
__device__ __forceinline__ s16x4 cvt4(float4 f) {
    s16x4 r; r[0] = f2bf(f.x); r[1] = f2bf(f.y); r[2] = f2bf(f.z); r[3] = f2bf(f.w);
    return r;
}
__device__ __forceinline__ s16x8 cat(s16x4 a, s16x4 b) {
    return __builtin_shufflevector(a, b, 0, 1, 2, 3, 4, 5, 6, 7);
}
__device__ __forceinline__ void nt_store4(float* p, f32x4 v) {
    __builtin_nontemporal_store(v, (f32x4*)p);   // global_store_dwordx4 ... nt
}

// ---------------- pre-pass: K -> bf16 row-major, V -> bf16 transposed ----------------
__global__ __launch_bounds__(256) void preconv(
    const float* __restrict__ K, const float* __restrict__ V,
    short* __restrict__ Kb, short* __restrict__ VT)
{
    const int bh  = blockIdx.x >> 6;
    const int seg = blockIdx.x & 63;
    const int tid = threadIdx.x;
    const float* Ks = K + ((size_t)bh * S_LEN + seg * 32) * D_K;
    const float* Vs = V + ((size_t)bh * S_LEN + seg * 32) * D_K;
    short* Kd  = Kb + ((size_t)bh * S_LEN + seg * 32) * D_K;
    short* VTd = VT + (size_t)bh * D_K * VT_STRIDE + seg * 32;

    for (int i = tid; i < 512; i += 256) {
        const int r = i >> 4, c = (i & 15) << 2;
        float4 f = *(const float4*)(Ks + r * D_K + c);
        *(s16x4*)(Kd + r * D_K + c) = cvt4(f);
    }
    for (int i = tid; i < 512; i += 256) {
        const int r = i & 31, c = (i >> 5) << 2;
        float4 f = *(const float4*)(Vs + r * D_K + c);
        VTd[(size_t)(c + 0) * VT_STRIDE + r] = f2bf(f.x);
        VTd[(size_t)(c + 1) * VT_STRIDE + r] = f2bf(f.y);
        VTd[(size_t)(c + 2) * VT_STRIDE + r] = f2bf(f.z);
        VTd[(size_t)(c + 3) * VT_STRIDE + r] = f2bf(f.w);
    }
}

// ---- main: one 16-row q-strip per block; waves own CONTIGUOUS k-tile ranges ----
// P-stores staged through per-wave LDS so every HBM store is full 128B lines.
#define CSTRIDE 66     // f32 elems per ctx-combine row (64 + 2 pad); 16*66 = 1056
#define SSTRIDE 33     // staging row stride (f32); 2 buffers * 16*33 = 1056 fits
__global__ __launch_bounds__(256) void attn_strip(
    const float* __restrict__ Q, const short* __restrict__ Kb,
    const short* __restrict__ VT, float* __restrict__ outC,
    float* __restrict__ outS)
{
    __shared__ float cbuf[4][16][CSTRIDE];   // per-wave: staging in-loop, ctx-combine after
    __shared__ float lbuf[4][16];            // per-wave partial row sums

    const int tid  = threadIdx.x;
    const int lane = tid & 63;
    const int wv   = tid >> 6;
    const int xcd  = blockIdx.x & 7;
    const int idx  = blockIdx.x >> 3;            // 0..511
    const int bh   = (xcd << 2) + (idx >> 7);    // 0..31, 4 heads per XCD
    const int strip = 127 - (idx & 127);         // heavy strips dispatched first
    const int q0w  = strip << 4;                 // strip's 16 q rows
    const int l15  = lane & 15;
    const int d0   = (lane >> 4) << 2;           // {0,4,8,12}
    const int qg   = q0w + l15;

    const short* Kbh = Kb + (size_t)bh * S_LEN * D_K;
    const short* VTh = VT + (size_t)bh * D_K * VT_STRIDE;
    float* outSb = outS + (size_t)bh * S_LEN * S_LEN;
    float* outCb = outC + (size_t)bh * S_LEN * D_K;
    float* stg = &cbuf[wv][0][0];                // 1056 f32 per wave, wave-private

    // Q as MFMA B-fragments (layout proven R0-R4)
    s16x8 qf0, qf1;
    {
        const float4* qp = (const float4*)(Q + ((size_t)bh * S_LEN + qg) * D_K);
        qf0 = cat(cvt4(qp[d0 >> 2]),        cvt4(qp[(d0 + 16) >> 2]));
        qf1 = cat(cvt4(qp[(d0 + 32) >> 2]), cvt4(qp[(d0 + 48) >> 2]));
    }

    const int ntiles = (strip >> 1) + 1;
    const int nfull  = strip >> 1;               // tiles strictly below diagonal
    const int nt4    = (ntiles + 3) >> 2;
    const int t0     = wv * nt4;
    const int t1     = (t0 + nt4 < ntiles) ? (t0 + nt4) : ntiles;
    const float scale = 0.125f;                  // 1/sqrt(64)

    // ---------- phase 1: partial row sums over this wave's contiguous k-range ----------
    float lsum = 0.f;
    for (int t = t0; t < t1; ++t) {
        const int k0 = t << 5;
        #pragma unroll
        for (int s = 0; s < 2; ++s) {
            const short* kp = Kbh + (size_t)(k0 + 16 * s + l15) * D_K + d0;
            s16x8 a0 = cat(*(const s16x4*)kp,        *(const s16x4*)(kp + 16));
            s16x8 a1 = cat(*(const s16x4*)(kp + 32), *(const s16x4*)(kp + 48));
            f32x4 c1 = {0.f, 0.f, 0.f, 0.f};
            c1 = __builtin_amdgcn_mfma_f32_16x16x32_bf16(a0, qf0, c1, 0, 0, 0);
            c1 = __builtin_amdgcn_mfma_f32_16x16x32_bf16(a1, qf1, c1, 0, 0, 0);
            if (t < nfull) {
                #pragma unroll
                for (int r = 0; r < 4; ++r) lsum += __expf(c1[r] * scale);
            } else {
                const int kbase = k0 + 16 * s + d0;
                #pragma unroll
                for (int r = 0; r < 4; ++r)
                    if (kbase + r <= qg) lsum += __expf(c1[r] * scale);
            }
        }
    }
    lsum += __shfl_xor(lsum, 16);
    lsum += __shfl_xor(lsum, 32);
    if (lane < 16) lbuf[wv][l15] = lsum;
    __syncthreads();
    const float rinv = 1.f / (lbuf[0][l15] + lbuf[1][l15] + lbuf[2][l15] + lbuf[3][l15]);

    // ---------- phase 2: P via LDS transpose -> full-line nt stores; partial P·V ----------
    const int srow = lane >> 3;                  // 0..7: store-lane row
    const int scol = (lane & 7) << 2;            // 0..28: store-lane col quad
    f32x4 ctx[4] = {{0,0,0,0},{0,0,0,0},{0,0,0,0},{0,0,0,0}};
    for (int t = t0; t < t1; ++t) {
        const int k0 = t << 5;
        const int buf = (t & 1) * (16 * SSTRIDE);
        s16x8 pf;
        #pragma unroll
        for (int s = 0; s < 2; ++s) {
            const short* kp = Kbh + (size_t)(k0 + 16 * s + l15) * D_K + d0;
            s16x8 a0 = cat(*(const s16x4*)kp,        *(const s16x4*)(kp + 16));
            s16x8 a1 = cat(*(const s16x4*)(kp + 32), *(const s16x4*)(kp + 48));
            f32x4 c1 = {0.f, 0.f, 0.f, 0.f};
            c1 = __builtin_amdgcn_mfma_f32_16x16x32_bf16(a0, qf0, c1, 0, 0, 0);
            c1 = __builtin_amdgcn_mfma_f32_16x16x32_bf16(a1, qf1, c1, 0, 0, 0);
            const int kbase = k0 + 16 * s + d0;
            f32x4 pw;
            if (t < nfull) {
                #pragma unroll
                for (int r = 0; r < 4; ++r) {
                    float pe = __expf(c1[r] * scale) * rinv;
                    pw[r] = pe; pf[4 * s + r] = f2bf(pe);
                }
            } else {
                #pragma unroll
                for (int r = 0; r < 4; ++r) {
                    float pe = (kbase + r <= qg) ? __expf(c1[r] * scale) * rinv : 0.f;
                    pw[r] = pe; pf[4 * s + r] = f2bf(pe);
                }
            }
            // stage 16x32 f32 tile: row = q (l15), col = 16s+d0..+3  (conflict-free)
            *(f32x4*)&stg[buf + l15 * SSTRIDE + 16 * s + d0] = pw;
        }
        #pragma unroll
        for (int db = 0; db < 4; ++db) {
            const short* vp = VTh + (size_t)(db * 16 + l15) * VT_STRIDE + k0 + d0;
            s16x8 b = cat(*(const s16x4*)vp, *(const s16x4*)(vp + 16));
            ctx[db] = __builtin_amdgcn_mfma_f32_16x16x32_bf16(pf, b, ctx[db], 0, 0, 0);
        }
        // wave-local flush: read back transposed (8 lanes/row -> 128B/row lines)
        asm volatile("s_waitcnt lgkmcnt(0)" ::: "memory");
        f32x4 w0 = *(const f32x4*)&stg[buf + srow * SSTRIDE + scol];
        f32x4 w1 = *(const f32x4*)&stg[buf + (srow + 8) * SSTRIDE + scol];
        nt_store4(outSb + (size_t)(q0w + srow) * S_LEN + k0 + scol, w0);
        nt_store4(outSb + (size_t)(q0w + 8 + srow) * S_LEN + k0 + scol, w1);
    }

    // combine partial ctx across the 4 waves via LDS
    __syncthreads();   // staging use done in all waves before cbuf reuse
    #pragma unroll
    for (int db = 0; db < 4; ++db)
        #pragma unroll
        for (int r = 0; r < 4; ++r)
            cbuf[wv][d0 + r][db * 16 + l15] = ctx[db][r];
    __syncthreads();
    {
        const int row = tid >> 4, dbase = (tid & 15) << 2;
        f32x4 acc = *(const f32x4*)&cbuf[0][row][dbase];
        #pragma unroll
        for (int w = 1; w < 4; ++w) {
            f32x4 p = *(const f32x4*)&cbuf[w][row][dbase];
            acc[0] += p[0]; acc[1] += p[1]; acc[2] += p[2]; acc[3] += p[3];
        }
        *(f32x4*)(outCb + (size_t)(q0w + row) * D_K + dbase) = acc;
    }

    // zero-fill masked region (k >= kz) of the strip's 16 rows, nontemporal
    const int kz = ntiles << 5;
    const f32x4 z = {0.f, 0.f, 0.f, 0.f};
    {
        const int row = tid >> 4;
        float* rowp = outSb + (size_t)(q0w + row) * S_LEN;
        for (int k = kz + ((tid & 15) << 2); k < S_LEN; k += 64)
            nt_store4(rowp + k, z);
    }
}

// ---------------- fallback (R0 kernel, proven) if ws too small ----------------
#define KSTRIDE 68
#define VSTRIDE 36
__global__ __launch_bounds__(256) void attn_causal_fb(
    const float* __restrict__ Q, const float* __restrict__ K,
    const float* __restrict__ V, float* __restrict__ outC,
    float* __restrict__ outS)
{
    __shared__ short Klds[32 * KSTRIDE];
    __shared__ short Vlds[64 * VSTRIDE];
    const int bh = blockIdx.x >> 5, q0 = (blockIdx.x & 31) << 6;
    const int tid = threadIdx.x, lane = tid & 63, wv = tid >> 6;
    const int q0w = q0 + (wv << 4), l15 = lane & 15, d0 = (lane >> 4) << 2;
    const int qg = q0w + l15, qhi = q0w + 15;
    const float* Kb = K + (size_t)bh * S_LEN * D_K;
    const float* Vb = V + (size_t)bh * S_LEN * D_K;
    float* outSb = outS + (size_t)bh * S_LEN * S_LEN;
    float* outCb = outC + (size_t)bh * S_LEN * D_K;
    s16x8 qf0, qf1;
    {
        const float4* qp = (const float4*)(Q + ((size_t)bh * S_LEN + qg) * D_K);
        qf0 = cat(cvt4(qp[d0 >> 2]), cvt4(qp[(d0 + 16) >> 2]));
        qf1 = cat(cvt4(qp[(d0 + 32) >> 2]), cvt4(qp[(d0 + 48) >> 2]));
    }
    const int npairs = (q0 >> 5) + 2;
    const float scale = 0.125f;
    float lsum = 0.f;
    for (int p = 0; p < npairs; ++p) {
        const int k0 = p << 5;
        for (int i = tid; i < 512; i += 256) {
            const int r = i >> 4, c = (i & 15) << 2;
            float4 f = *(const float4*)(Kb + (size_t)(k0 + r) * D_K + c);
            *(s16x4*)&Klds[r * KSTRIDE + c] = cvt4(f);
        }
        __syncthreads();
        if (k0 <= qhi) {
            #pragma unroll
            for (int s = 0; s < 2; ++s) {
                const short* kp = &Klds[(16 * s + l15) * KSTRIDE + d0];
                s16x8 a0 = cat(*(const s16x4*)kp, *(const s16x4*)(kp + 16));
                s16x8 a1 = cat(*(const s16x4*)(kp + 32), *(const s16x4*)(kp + 48));
                f32x4 c1 = {0.f, 0.f, 0.f, 0.f};
                c1 = __builtin_amdgcn_mfma_f32_16x16x32_bf16(a0, qf0, c1, 0, 0, 0);
                c1 = __builtin_amdgcn_mfma_f32_16x16x32_bf16(a1, qf1, c1, 0, 0, 0);
                const int kbase = k0 + 16 * s + d0;
                #pragma unroll
                for (int r = 0; r < 4; ++r)
                    if (kbase + r <= qg) lsum += __expf(c1[r] * scale);
            }
        }
        __syncthreads();
    }
    lsum += __shfl_xor(lsum, 16);
    lsum += __shfl_xor(lsum, 32);
    const float rinv = 1.f / lsum;
    f32x4 ctx[4] = {{0,0,0,0},{0,0,0,0},{0,0,0,0},{0,0,0,0}};
    for (int p = 0; p < npairs; ++p) {
        const int k0 = p << 5;
        for (int i = tid; i < 512; i += 256) {
            const int r = i >> 4, c = (i & 15) << 2;
            float4 f = *(const float4*)(Kb + (size_t)(k0 + r) * D_K + c);
            *(s16x4*)&Klds[r * KSTRIDE + c] = cvt4(f);
            float4 g = *(const float4*)(Vb + (size_t)(k0 + r) * D_K + c);
            Vlds[(c + 0) * VSTRIDE + r] = f2bf(g.x);
            Vlds[(c + 1) * VSTRIDE + r] = f2bf(g.y);
            Vlds[(c + 2) * VSTRIDE + r] = f2bf(g.z);
            Vlds[(c + 3) * VSTRIDE + r] = f2bf(g.w);
        }
        __syncthreads();
        if (k0 <= qhi) {
            s16x8 pf;
            #pragma unroll
            for (int s = 0; s < 2; ++s) {
                const short* kp = &Klds[(16 * s + l15) * KSTRIDE + d0];
                s16x8 a0 = cat(*(const s16x4*)kp, *(const s16x4*)(kp + 16));
                s16x8 a1 = cat(*(const s16x4*)(kp + 32), *(const s16x4*)(kp + 48));
                f32x4 c1 = {0.f, 0.f, 0.f, 0.f};
                c1 = __builtin_amdgcn_mfma_f32_16x16x32_bf16(a0, qf0, c1, 0, 0, 0);
                c1 = __builtin_amdgcn_mfma_f32_16x16x32_bf16(a1, qf1, c1, 0, 0, 0);
                const int kbase = k0 + 16 * s + d0;
                f32x4 pw;
                #pragma unroll
                for (int r = 0; r < 4; ++r) {
                    float pe = (kbase + r <= qg) ? __expf(c1[r] * scale) * rinv : 0.f;
                    pw[r] = pe;
                    pf[4 * s + r] = f2bf(pe);
                }
                *(f32x4*)(outSb + (size_t)qg * S_LEN + kbase) = pw;
            }
            #pragma unroll
            for (int db = 0; db < 4; ++db) {
                const short* vp = &Vlds[(db * 16 + l15) * VSTRIDE + d0];
                s16x8 b = cat(*(const s16x4*)vp, *(const s16x4*)(vp + 16));
                ctx[db] = __builtin_amdgcn_mfma_f32_16x16x32_bf16(pf, b, ctx[db], 0, 0, 0);
            }
        }
        __syncthreads();
    }
    #pragma unroll
    for (int db = 0; db < 4; ++db)
        #pragma unroll
        for (int r = 0; r < 4; ++r)
            outCb[(size_t)(q0w + d0 + r) * D_K + db * 16 + l15] = ctx[db][r];
    const int kz = ((qhi >> 5) + 1) << 5;
    const f32x4 z = {0.f, 0.f, 0.f, 0.f};
    for (int r = 0; r < 16; ++r) {
        float* rowp = outSb + (size_t)(q0w + r) * S_LEN;
        for (int k = kz + (lane << 2); k < S_LEN; k += 256)
            *(f32x4*)(rowp + k) = z;
    }
}

extern "C" void kernel_launch(void* const* d_in, const int* in_sizes, int n_in,
                              void* d_out, int out_size, void* d_ws, size_t ws_size,
                              hipStream_t stream) {
    const float* Q = (const float*)d_in[0];
    const float* K = (const float*)d_in[1];
    const float* V = (const float*)d_in[2];
    float* outC = (float*)d_out;
    float* outS = (float*)d_out + (size_t)NBH * S_LEN * D_K;

    const size_t kb_elems = (size_t)NBH * S_LEN * D_K;
    const size_t vt_elems = (size_t)NBH * D_K * VT_STRIDE;
    const size_t need = (kb_elems + vt_elems) * sizeof(short);

    if (ws_size >= need) {
        short* Kb = (short*)d_ws;
        short* VT = Kb + kb_elems;
        preconv<<<dim3(NBH * 64), dim3(256), 0, stream>>>(K, V, Kb, VT);
        attn_strip<<<dim3(4096), dim3(256), 0, stream>>>(Q, Kb, VT, outC, outS);
    } else {
        attn_causal_fb<<<dim3(1024), dim3(256), 0, stream>>>(Q, K, V, outC, outS);
    }
}

// Round 6
// 343.936 us; speedup vs baseline: 1.7516x; 1.0091x over previous
//
#include <hip/hip_runtime.h>
#include <stdint.h>

typedef float  f32x4  __attribute__((ext_vector_type(4)));
typedef short  s16x4  __attribute__((ext_vector_type(4)));
typedef short  s16x8  __attribute__((ext_vector_type(8)));

#define S_LEN 2048
#define D_K   64
#define NBH   32
#define VT_STRIDE (S_LEN + 32)   // pad V^T rows to stagger L2 sets

__device__ __forceinline__ short f2bf(float f) {
    uint32_t u = __builtin_bit_cast(uint32_t, f);
    u += 0x7fffu + ((u >> 16) & 1u);           // RNE
    return (short)(u >> 16);
}
__device__ __forceinline__ s16x4 cvt4(float4 f) {
    s16x4 r; r[0] = f2bf(f.x); r[1] = f2bf(f.y); r[2] = f2bf(f.z); r[3] = f2bf(f.w);
    return r;
}
__device__ __forceinline__ s16x8 cat(s16x4 a, s16x4 b) {
    return __builtin_shufflevector(a, b, 0, 1, 2, 3, 4, 5, 6, 7);
}
__device__ __forceinline__ void nt_store4(float* p, f32x4 v) {
    __builtin_nontemporal_store(v, (f32x4*)p);   // global_store_dwordx4 ... nt
}

// ---------------- pre-pass: K -> bf16 row-major, V -> bf16 transposed ----------------
__global__ __launch_bounds__(256) void preconv(
    const float* __restrict__ K, const float* __restrict__ V,
    short* __restrict__ Kb, short* __restrict__ VT)
{
    const int bh  = blockIdx.x >> 6;
    const int seg = blockIdx.x & 63;
    const int tid = threadIdx.x;
    const float* Ks = K + ((size_t)bh * S_LEN + seg * 32) * D_K;
    const float* Vs = V + ((size_t)bh * S_LEN + seg * 32) * D_K;
    short* Kd  = Kb + ((size_t)bh * S_LEN + seg * 32) * D_K;
    short* VTd = VT + (size_t)bh * D_K * VT_STRIDE + seg * 32;

    for (int i = tid; i < 512; i += 256) {
        const int r = i >> 4, c = (i & 15) << 2;
        float4 f = *(const float4*)(Ks + r * D_K + c);
        *(s16x4*)(Kd + r * D_K + c) = cvt4(f);
    }
    for (int i = tid; i < 512; i += 256) {
        const int r = i & 31, c = (i >> 5) << 2;
        float4 f = *(const float4*)(Vs + r * D_K + c);
        VTd[(size_t)(c + 0) * VT_STRIDE + r] = f2bf(f.x);
        VTd[(size_t)(c + 1) * VT_STRIDE + r] = f2bf(f.y);
        VTd[(size_t)(c + 2) * VT_STRIDE + r] = f2bf(f.z);
        VTd[(size_t)(c + 3) * VT_STRIDE + r] = f2bf(f.w);
    }
}

// ---- main: one 16-row q-strip per block; P staged 16x512 in LDS, flushed
// ---- ROW-SEQUENTIALLY so HBM sees few, long write streams per block.
#define CSTRIDE 66     // f32 per ctx-combine row (64 + 2 pad)
#define PSTRIDE 516    // f32 per staging row (512 + 4 pad -> 2-way banks only)
#define CHUNK_T 16     // k-tiles per flush chunk (512 columns)
__global__ __launch_bounds__(256) void attn_strip(
    const float* __restrict__ Q, const short* __restrict__ Kb,
    const short* __restrict__ VT, float* __restrict__ outC,
    float* __restrict__ outS)
{
    __shared__ float pstg[16 * PSTRIDE];     // 33 KB score staging
    __shared__ float cbuf[4][16][CSTRIDE];   // per-wave partial ctx
    __shared__ float lbuf[4][16];            // per-wave partial row sums

    const int tid  = threadIdx.x;
    const int lane = tid & 63;
    const int wv   = tid >> 6;
    const int xcd  = blockIdx.x & 7;
    const int idx  = blockIdx.x >> 3;            // 0..511
    const int bh   = (xcd << 2) + (idx >> 7);    // 0..31, 4 heads per XCD
    const int strip = 127 - (idx & 127);         // heavy strips dispatched first
    const int q0w  = strip << 4;                 // strip's 16 q rows
    const int l15  = lane & 15;
    const int d0   = (lane >> 4) << 2;           // {0,4,8,12}
    const int qg   = q0w + l15;

    const short* Kbh = Kb + (size_t)bh * S_LEN * D_K;
    const short* VTh = VT + (size_t)bh * D_K * VT_STRIDE;
    float* outSb = outS + (size_t)bh * S_LEN * S_LEN;
    float* outCb = outC + (size_t)bh * S_LEN * D_K;

    // Q as MFMA B-fragments (layout proven R0-R5)
    s16x8 qf0, qf1;
    {
        const float4* qp = (const float4*)(Q + ((size_t)bh * S_LEN + qg) * D_K);
        qf0 = cat(cvt4(qp[d0 >> 2]),        cvt4(qp[(d0 + 16) >> 2]));
        qf1 = cat(cvt4(qp[(d0 + 32) >> 2]), cvt4(qp[(d0 + 48) >> 2]));
    }

    const int ntiles = (strip >> 1) + 1;         // 1..64
    const int nfull  = strip >> 1;               // tiles strictly below diagonal
    const float scale = 0.125f;                  // 1/sqrt(64)

    // ---------- phase 1: partial row sums, tiles strided across waves ----------
    float lsum = 0.f;
    for (int t = wv; t < ntiles; t += 4) {
        const int k0 = t << 5;
        #pragma unroll
        for (int s = 0; s < 2; ++s) {
            const short* kp = Kbh + (size_t)(k0 + 16 * s + l15) * D_K + d0;
            s16x8 a0 = cat(*(const s16x4*)kp,        *(const s16x4*)(kp + 16));
            s16x8 a1 = cat(*(const s16x4*)(kp + 32), *(const s16x4*)(kp + 48));
            f32x4 c1 = {0.f, 0.f, 0.f, 0.f};
            c1 = __builtin_amdgcn_mfma_f32_16x16x32_bf16(a0, qf0, c1, 0, 0, 0);
            c1 = __builtin_amdgcn_mfma_f32_16x16x32_bf16(a1, qf1, c1, 0, 0, 0);
            if (t < nfull) {
                #pragma unroll
                for (int r = 0; r < 4; ++r) lsum += __expf(c1[r] * scale);
            } else {
                const int kbase = k0 + 16 * s + d0;
                #pragma unroll
                for (int r = 0; r < 4; ++r)
                    if (kbase + r <= qg) lsum += __expf(c1[r] * scale);
            }
        }
    }
    lsum += __shfl_xor(lsum, 16);
    lsum += __shfl_xor(lsum, 32);
    if (lane < 16) lbuf[wv][l15] = lsum;
    __syncthreads();
    const float rinv = 1.f / (lbuf[0][l15] + lbuf[1][l15] + lbuf[2][l15] + lbuf[3][l15]);

    // ---------- phase 2: chunked -> LDS staging -> row-sequential flush ----------
    f32x4 ctx[4] = {{0,0,0,0},{0,0,0,0},{0,0,0,0},{0,0,0,0}};
    for (int cb = 0; cb < ntiles; cb += CHUNK_T) {
        const int tend = (cb + CHUNK_T < ntiles) ? (cb + CHUNK_T) : ntiles;
        for (int t = cb + wv; t < tend; t += 4) {
            const int k0 = t << 5;
            const int tt = t - cb;
            s16x8 pf;
            #pragma unroll
            for (int s = 0; s < 2; ++s) {
                const short* kp = Kbh + (size_t)(k0 + 16 * s + l15) * D_K + d0;
                s16x8 a0 = cat(*(const s16x4*)kp,        *(const s16x4*)(kp + 16));
                s16x8 a1 = cat(*(const s16x4*)(kp + 32), *(const s16x4*)(kp + 48));
                f32x4 c1 = {0.f, 0.f, 0.f, 0.f};
                c1 = __builtin_amdgcn_mfma_f32_16x16x32_bf16(a0, qf0, c1, 0, 0, 0);
                c1 = __builtin_amdgcn_mfma_f32_16x16x32_bf16(a1, qf1, c1, 0, 0, 0);
                const int kbase = k0 + 16 * s + d0;
                f32x4 pw;
                if (t < nfull) {
                    #pragma unroll
                    for (int r = 0; r < 4; ++r) {
                        float pe = __expf(c1[r] * scale) * rinv;
                        pw[r] = pe; pf[4 * s + r] = f2bf(pe);
                    }
                } else {
                    #pragma unroll
                    for (int r = 0; r < 4; ++r) {
                        float pe = (kbase + r <= qg) ? __expf(c1[r] * scale) * rinv : 0.f;
                        pw[r] = pe; pf[4 * s + r] = f2bf(pe);
                    }
                }
                *(f32x4*)&pstg[l15 * PSTRIDE + tt * 32 + 16 * s + d0] = pw;
            }
            #pragma unroll
            for (int db = 0; db < 4; ++db) {
                const short* vp = VTh + (size_t)(db * 16 + l15) * VT_STRIDE + k0 + d0;
                s16x8 b = cat(*(const s16x4*)vp, *(const s16x4*)(vp + 16));
                ctx[db] = __builtin_amdgcn_mfma_f32_16x16x32_bf16(pf, b, ctx[db], 0, 0, 0);
            }
        }
        __syncthreads();   // staging complete (implies lgkm drain)
        // flush: 2 rows per iteration, each row 2KB contiguous (128 thr x 16B)
        const int W = (tend - cb) << 5;          // valid cols this chunk
        const int frow = tid >> 7;               // 0..1
        const int fcol = (tid & 127) << 2;       // 0..508
        const size_t gbase = (size_t)q0w * S_LEN + ((size_t)cb << 5);
        if (fcol < W) {
            #pragma unroll
            for (int rp = 0; rp < 16; rp += 2) {
                const int row = rp + frow;
                nt_store4(outSb + gbase + (size_t)row * S_LEN + fcol,
                          *(const f32x4*)&pstg[row * PSTRIDE + fcol]);
            }
        }
        __syncthreads();   // flush done before staging reuse
    }

    // combine partial ctx across the 4 waves via LDS
    #pragma unroll
    for (int db = 0; db < 4; ++db)
        #pragma unroll
        for (int r = 0; r < 4; ++r)
            cbuf[wv][d0 + r][db * 16 + l15] = ctx[db][r];
    __syncthreads();
    {
        const int row = tid >> 4, dbase = (tid & 15) << 2;
        f32x4 acc = *(const f32x4*)&cbuf[0][row][dbase];
        #pragma unroll
        for (int w = 1; w < 4; ++w) {
            f32x4 p = *(const f32x4*)&cbuf[w][row][dbase];
            acc[0] += p[0]; acc[1] += p[1]; acc[2] += p[2]; acc[3] += p[3];
        }
        *(f32x4*)(outCb + (size_t)(q0w + row) * D_K + dbase) = acc;
    }

    // zero-fill masked region: row-sequential, 4KB contiguous per block-step
    const int kz = ntiles << 5;
    const f32x4 z = {0.f, 0.f, 0.f, 0.f};
    {
        const int c0 = tid << 2;                 // 256 thr x 4 f32 = 1024 f32/step
        for (int r = 0; r < 16; ++r) {
            float* rowp = outSb + (size_t)(q0w + r) * S_LEN;
            for (int k = kz + c0; k < S_LEN; k += 1024)
                nt_store4(rowp + k, z);
        }
    }
}

// ---------------- fallback (R0 kernel, proven) if ws too small ----------------
#define KSTRIDE 68
#define VSTRIDE 36
__global__ __launch_bounds__(256) void attn_causal_fb(
    const float* __restrict__ Q, const float* __restrict__ K,
    const float* __restrict__ V, float* __restrict__ outC,
    float* __restrict__ outS)
{
    __shared__ short Klds[32 * KSTRIDE];
    __shared__ short Vlds[64 * VSTRIDE];
    const int bh = blockIdx.x >> 5, q0 = (blockIdx.x & 31) << 6;
    const int tid = threadIdx.x, lane = tid & 63, wv = tid >> 6;
    const int q0w = q0 + (wv << 4), l15 = lane & 15, d0 = (lane >> 4) << 2;
    const int qg = q0w + l15, qhi = q0w + 15;
    const float* Kb = K + (size_t)bh * S_LEN * D_K;
    const float* Vb = V + (size_t)bh * S_LEN * D_K;
    float* outSb = outS + (size_t)bh * S_LEN * S_LEN;
    float* outCb = outC + (size_t)bh * S_LEN * D_K;
    s16x8 qf0, qf1;
    {
        const float4* qp = (const float4*)(Q + ((size_t)bh * S_LEN + qg) * D_K);
        qf0 = cat(cvt4(qp[d0 >> 2]), cvt4(qp[(d0 + 16) >> 2]));
        qf1 = cat(cvt4(qp[(d0 + 32) >> 2]), cvt4(qp[(d0 + 48) >> 2]));
    }
    const int npairs = (q0 >> 5) + 2;
    const float scale = 0.125f;
    float lsum = 0.f;
    for (int p = 0; p < npairs; ++p) {
        const int k0 = p << 5;
        for (int i = tid; i < 512; i += 256) {
            const int r = i >> 4, c = (i & 15) << 2;
            float4 f = *(const float4*)(Kb + (size_t)(k0 + r) * D_K + c);
            *(s16x4*)&Klds[r * KSTRIDE + c] = cvt4(f);
        }
        __syncthreads();
        if (k0 <= qhi) {
            #pragma unroll
            for (int s = 0; s < 2; ++s) {
                const short* kp = &Klds[(16 * s + l15) * KSTRIDE + d0];
                s16x8 a0 = cat(*(const s16x4*)kp, *(const s16x4*)(kp + 16));
                s16x8 a1 = cat(*(const s16x4*)(kp + 32), *(const s16x4*)(kp + 48));
                f32x4 c1 = {0.f, 0.f, 0.f, 0.f};
                c1 = __builtin_amdgcn_mfma_f32_16x16x32_bf16(a0, qf0, c1, 0, 0, 0);
                c1 = __builtin_amdgcn_mfma_f32_16x16x32_bf16(a1, qf1, c1, 0, 0, 0);
                const int kbase = k0 + 16 * s + d0;
                #pragma unroll
                for (int r = 0; r < 4; ++r)
                    if (kbase + r <= qg) lsum += __expf(c1[r] * scale);
            }
        }
        __syncthreads();
    }
    lsum += __shfl_xor(lsum, 16);
    lsum += __shfl_xor(lsum, 32);
    const float rinv = 1.f / lsum;
    f32x4 ctx[4] = {{0,0,0,0},{0,0,0,0},{0,0,0,0},{0,0,0,0}};
    for (int p = 0; p < npairs; ++p) {
        const int k0 = p << 5;
        for (int i = tid; i < 512; i += 256) {
            const int r = i >> 4, c = (i & 15) << 2;
            float4 f = *(const float4*)(Kb + (size_t)(k0 + r) * D_K + c);
            *(s16x4*)&Klds[r * KSTRIDE + c] = cvt4(f);
            float4 g = *(const float4*)(Vb + (size_t)(k0 + r) * D_K + c);
            Vlds[(c + 0) * VSTRIDE + r] = f2bf(g.x);
            Vlds[(c + 1) * VSTRIDE + r] = f2bf(g.y);
            Vlds[(c + 2) * VSTRIDE + r] = f2bf(g.z);
            Vlds[(c + 3) * VSTRIDE + r] = f2bf(g.w);
        }
        __syncthreads();
        if (k0 <= qhi) {
            s16x8 pf;
            #pragma unroll
            for (int s = 0; s < 2; ++s) {
                const short* kp = &Klds[(16 * s + l15) * KSTRIDE + d0];
                s16x8 a0 = cat(*(const s16x4*)kp, *(const s16x4*)(kp + 16));
                s16x8 a1 = cat(*(const s16x4*)(kp + 32), *(const s16x4*)(kp + 48));
                f32x4 c1 = {0.f, 0.f, 0.f, 0.f};
                c1 = __builtin_amdgcn_mfma_f32_16x16x32_bf16(a0, qf0, c1, 0, 0, 0);
                c1 = __builtin_amdgcn_mfma_f32_16x16x32_bf16(a1, qf1, c1, 0, 0, 0);
                const int kbase = k0 + 16 * s + d0;
                f32x4 pw;
                #pragma unroll
                for (int r = 0; r < 4; ++r) {
                    float pe = (kbase + r <= qg) ? __expf(c1[r] * scale) * rinv : 0.f;
                    pw[r] = pe;
                    pf[4 * s + r] = f2bf(pe);
                }
                *(f32x4*)(outSb + (size_t)qg * S_LEN + kbase) = pw;
            }
            #pragma unroll
            for (int db = 0; db < 4; ++db) {
                const short* vp = &Vlds[(db * 16 + l15) * VSTRIDE + d0];
                s16x8 b = cat(*(const s16x4*)vp, *(const s16x4*)(vp + 16));
                ctx[db] = __builtin_amdgcn_mfma_f32_16x16x32_bf16(pf, b, ctx[db], 0, 0, 0);
            }
        }
        __syncthreads();
    }
    #pragma unroll
    for (int db = 0; db < 4; ++db)
        #pragma unroll
        for (int r = 0; r < 4; ++r)
            outCb[(size_t)(q0w + d0 + r) * D_K + db * 16 + l15] = ctx[db][r];
    const int kz = ((qhi >> 5) + 1) << 5;
    const f32x4 z = {0.f, 0.f, 0.f, 0.f};
    for (int r = 0; r < 16; ++r) {
        float* rowp = outSb + (size_t)(q0w + r) * S_LEN;
        for (int k = kz + (lane << 2); k < S_LEN; k += 256)
            *(f32x4*)(rowp + k) = z;
    }
}

extern "C" void kernel_launch(void* const* d_in, const int* in_sizes, int n_in,
                              void* d_out, int out_size, void* d_ws, size_t ws_size,
                              hipStream_t stream) {
    const float* Q = (const float*)d_in[0];
    const float* K = (const float*)d_in[1];
    const float* V = (const float*)d_in[2];
    float* outC = (float*)d_out;
    float* outS = (float*)d_out + (size_t)NBH * S_LEN * D_K;

    const size_t kb_elems = (size_t)NBH * S_LEN * D_K;
    const size_t vt_elems = (size_t)NBH * D_K * VT_STRIDE;
    const size_t need = (kb_elems + vt_elems) * sizeof(short);

    if (ws_size >= need) {
        short* Kb = (short*)d_ws;
        short* VT = Kb + kb_elems;
        preconv<<<dim3(NBH * 64), dim3(256), 0, stream>>>(K, V, Kb, VT);
        attn_strip<<<dim3(4096), dim3(256), 0, stream>>>(Q, Kb, VT, outC, outS);
    } else {
        attn_causal_fb<<<dim3(1024), dim3(256), 0, stream>>>(Q, K, V, outC, outS);
    }
}